// Round 4
// baseline (1747.420 us; speedup 1.0000x reference)
//
#include <hip/hip_runtime.h>

typedef float v2f __attribute__((ext_vector_type(2)));

#define HID 32

__device__ __forceinline__ float sigmoidf_fast(float x) {
    return __fdividef(1.0f, 1.0f + __expf(-x));
}
__device__ __forceinline__ float tanhf_fast(float x) {
    // tanh(x) = 1 - 2/(1+e^{2x}); saturates correctly
    return 1.0f - __fdividef(2.0f, 1.0f + __expf(2.0f * x));
}

// Packed fp32 FMA, forced: 1 inst per 2 MACs, and every operand must live in
// arch VGPRs at every use site (defeats the AGPR-shelving + scalarization the
// compiler chose in R2/R3 — VGPR_Count stuck at 104 with ~400 issue/step).
#define PKFMA(acc, w, h) \
    asm("v_pk_fma_f32 %0, %1, %2, %0" : "+v"(acc) : "v"(w), "v"(h))

// xor-butterfly add within 32-lane groups (ds_swizzle bit-mode, and=0x1F)
#define SWZ_ADD(p, imm) do {                                            \
    int _t = __builtin_amdgcn_ds_swizzle(__float_as_int(p), (imm));     \
    (p) += __int_as_float(_t); } while (0)
#define REDUCE32(p) do {                                                \
    SWZ_ADD(p, 0x041F); SWZ_ADD(p, 0x081F); SWZ_ADD(p, 0x101F);        \
    SWZ_ADD(p, 0x201F); SWZ_ADD(p, 0x401F); } while (0)

__global__ __launch_bounds__(256, 2)
void lstm_persist(const float* __restrict__ poses,
                  const float* __restrict__ W_ih,
                  const float* __restrict__ W_hh,
                  const float* __restrict__ W_dense,
                  float* __restrict__ out,
                  int B, int T_enc, int T_dec)
{
    // 8 elements per 256-thread block, 32 lanes per element.
    __shared__ __align__(16) float hx[8][HID];

    const int tid = threadIdx.x;
    const int k   = tid & 31;          // hidden unit owned by this lane
    const int eb  = tid >> 5;          // element within block (0..7)
    const int el  = blockIdx.x * 8 + eb;

    // ---- persistent weights: rows k, k+32, k+64, k+96 as v2f pairs ----
    const v2f* Wih2 = reinterpret_cast<const v2f*>(W_ih);
    v2f wi01 = Wih2[2*k],        wi23 = Wih2[2*k + 1];
    v2f wf01 = Wih2[2*(k+32)],   wf23 = Wih2[2*(k+32) + 1];
    v2f wg01 = Wih2[2*(k+64)],   wg23 = Wih2[2*(k+64) + 1];
    v2f wo01 = Wih2[2*(k+96)],   wo23 = Wih2[2*(k+96) + 1];

    v2f whh_i[16], whh_f[16], whh_g[16], whh_o[16];   // 128 VGPRs, loaded ONCE
    {
        const v2f* Whh2 = reinterpret_cast<const v2f*>(W_hh);
        #pragma unroll
        for (int j = 0; j < 16; ++j) {
            whh_i[j] = Whh2[(k     ) * 16 + j];
            whh_f[j] = Whh2[(k + 32) * 16 + j];
            whh_g[j] = Whh2[(k + 64) * 16 + j];
            whh_o[j] = Whh2[(k + 96) * 16 + j];
        }
    }
    const float wd1 = W_dense[HID + k];
    const float wd2 = W_dense[2 * HID + k];

    v2f h2[16];
    #pragma unroll
    for (int j = 0; j < 16; ++j) h2[j] = (v2f){0.f, 0.f};
    float c = 0.f, hk = 0.f;

    const float4* poses4 = reinterpret_cast<const float4*>(poses);
    float4*       out4   = reinterpret_cast<float4*>(out);

    auto lstm_step = [&](float xx, float xy, float xz, float xw) {
        const v2f x01 = {xx, xy}, x23 = {xz, xw};
        v2f ai = {0.f, 0.f}, af = {0.f, 0.f}, ag = {0.f, 0.f}, ao = {0.f, 0.f};
        PKFMA(ai, wi01, x01); PKFMA(ai, wi23, x23);
        PKFMA(af, wf01, x01); PKFMA(af, wf23, x23);
        PKFMA(ag, wg01, x01); PKFMA(ag, wg23, x23);
        PKFMA(ao, wo01, x01); PKFMA(ao, wo23, x23);
        #pragma unroll
        for (int j = 0; j < 16; ++j) {      // 4 independent pk_fma chains
            PKFMA(ai, whh_i[j], h2[j]);
            PKFMA(af, whh_f[j], h2[j]);
            PKFMA(ag, whh_g[j], h2[j]);
            PKFMA(ao, whh_o[j], h2[j]);
        }
        const float gi = ai.x + ai.y, gf = af.x + af.y;
        const float gg = ag.x + ag.y, go = ao.x + ao.y;
        const float ii = sigmoidf_fast(gi);
        const float ff = sigmoidf_fast(gf);
        const float gt = tanhf_fast(gg);
        const float oo = sigmoidf_fast(go);
        c  = ff * c + ii * gt;              // c stays in this lane forever
        hk = oo * tanhf_fast(c);
        // intra-wave h exchange: half-wave-private row, no barrier needed
        hx[eb][k] = hk;
        const v2f* hr = reinterpret_cast<const v2f*>(&hx[eb][0]);
        #pragma unroll
        for (int j = 0; j < 16; ++j) h2[j] = hr[j];   // merged ds_read, aligned pairs
    };

    // ---------------- encoder (x prefetched one step ahead) ----------------
    float4 x = poses4[el];
    for (int t = 0; t < T_enc; ++t) {
        float4 xn = x;
        if (t + 1 < T_enc) xn = poses4[(size_t)(t + 1) * B + el];
        lstm_step(x.x, x.y, x.z, x.w);
        x = xn;
    }
    const float px = x.x, py = x.y;         // poses[-1][:,:2], constant in decode

    float v1 = wd1 * hk, v2 = wd2 * hk;     // vel rows 1,2 (row 0 unused)
    REDUCE32(v1); REDUCE32(v2);

    // ---------------- decoder ----------------
    for (int t = 0; t < T_dec; ++t) {
        const float rn = rsqrtf(v1 * v1 + v2 * v2);
        const float cs = v1 * rn, sn = v2 * rn;
        if (k == 0) out4[(size_t)t * B + el] = make_float4(px, py, cs, sn);
        lstm_step(px, py, cs, sn);
        v1 = wd1 * hk; v2 = wd2 * hk;
        REDUCE32(v1); REDUCE32(v2);
    }
}

extern "C" void kernel_launch(void* const* d_in, const int* in_sizes, int n_in,
                              void* d_out, int out_size, void* d_ws, size_t ws_size,
                              hipStream_t stream) {
    const float* poses   = (const float*)d_in[0];
    // d_in[1] = deltas: values unused by the reference decoder (only length matters)
    const float* W_ih    = (const float*)d_in[2];
    const float* W_hh    = (const float*)d_in[3];
    const float* W_dense = (const float*)d_in[4];
    float* out = (float*)d_out;

    const int T_enc = 64;                       // fixed by the reference setup
    const int B     = in_sizes[0] / (T_enc * 4);
    const int T_dec = out_size / (B * 4);       // n_new_poses

    dim3 grid(B / 8), block(256);
    hipLaunchKernelGGL(lstm_persist, grid, block, 0, stream,
                       poses, W_ih, W_hh, W_dense, out, B, T_enc, T_dec);
}

// Round 5
// 1485.115 us; speedup vs baseline: 1.1766x; 1.1766x over previous
//
#include <hip/hip_runtime.h>

typedef float v2f __attribute__((ext_vector_type(2)));

#define HID 32
#define LOG2E 1.4426950408889634f

#if __has_builtin(__builtin_amdgcn_exp2f)
#define EXP2(x) __builtin_amdgcn_exp2f(x)
#else
#define EXP2(x) exp2f(x)
#endif
#if __has_builtin(__builtin_amdgcn_rcpf)
#define RCP(x) __builtin_amdgcn_rcpf(x)
#else
#define RCP(x) (1.0f / (x))
#endif

// Packed fp32 FMA (1 inst / 2 MACs). Non-volatile: scheduler may reorder.
#define PKFMA(acc, w, h) \
    asm("v_pk_fma_f32 %0, %1, %2, %0" : "+v"(acc) : "v"(w), "v"(h))

// xor-butterfly add within 32-lane groups (each group holds every hidden unit
// exactly once, so both halves converge to the same full sum independently)
#define SWZ_ADD(p, imm) do {                                            \
    int _t = __builtin_amdgcn_ds_swizzle(__float_as_int(p), (imm));     \
    (p) += __int_as_float(_t); } while (0)
#define REDUCE32(p) do {                                                \
    SWZ_ADD(p, 0x041F); SWZ_ADD(p, 0x081F); SWZ_ADD(p, 0x101F);        \
    SWZ_ADD(p, 0x201F); SWZ_ADD(p, 0x401F); } while (0)

// waves_per_eu(3,4): reg budget 168/wave — the allocator's 5-wave default
// (104 regs) demoted our 144-reg weight set in R2-R4; 72-reg/lane layout +
// this budget removes any reason to shelve weights off the arch file.
__global__ __attribute__((amdgpu_waves_per_eu(3, 4))) __launch_bounds__(256)
void lstm_gatesplit(const float* __restrict__ poses,
                    const float* __restrict__ W_ih,
                    const float* __restrict__ W_hh,
                    const float* __restrict__ W_dense,
                    float* __restrict__ out,
                    int B, int T_enc, int T_dec)
{
    // one element per wave; hx row is wave-private -> NO barriers anywhere
    __shared__ __align__(16) float hx[4][HID];

    const int tid  = threadIdx.x;
    const int lane = tid & 63;
    const int wv   = tid >> 6;          // wave within block (0..3)
    const int k    = lane & 31;         // hidden unit
    const int isH  = lane >> 5;         // 0: rows {k, 64+k}=(i,g); 1: {32+k, 96+k}=(f,o)
    const int el   = blockIdx.x * 4 + wv;

    const int rowA = isH * 32 + k;      // i or f
    const int rowB = rowA + 64;         // g or o

    // ---- persistent weights: 72 floats/lane ----
    const v2f* Wih2 = reinterpret_cast<const v2f*>(W_ih);
    v2f wA0 = Wih2[2 * rowA], wA1 = Wih2[2 * rowA + 1];
    v2f wB0 = Wih2[2 * rowB], wB1 = Wih2[2 * rowB + 1];
    v2f whhA[16], whhB[16];
    {
        const v2f* Whh2 = reinterpret_cast<const v2f*>(W_hh);
        #pragma unroll
        for (int j = 0; j < 16; ++j) {
            whhA[j] = Whh2[rowA * 16 + j];
            whhB[j] = Whh2[rowB * 16 + j];
        }
    }
    const float wd1 = W_dense[HID + k];
    const float wd2 = W_dense[2 * HID + k];

    // branchless activation selectors: rowA is always sigmoid; rowB is
    // tanh (half 0) or sigmoid (half 1): act1 = A1 + B1 * rcp(1 + 2^(S1*a1))
    const float S1 = isH ? -LOG2E : 2.0f * LOG2E;
    const float A1 = isH ? 0.0f : 1.0f;
    const float B1 = isH ? 1.0f : -2.0f;

    v2f h2[16];
    #pragma unroll
    for (int j = 0; j < 16; ++j) h2[j] = (v2f){0.f, 0.f};
    float c = 0.f, hk = 0.f;            // both halves keep identical copies

    const float4* poses4 = reinterpret_cast<const float4*>(poses);
    float4*       out4   = reinterpret_cast<float4*>(out);

    auto lstm_step = [&](v2f x01, v2f x23) {
        v2f aA = {0.f, 0.f}, aB = {0.f, 0.f};
        PKFMA(aA, wA0, x01); PKFMA(aA, wA1, x23);
        PKFMA(aB, wB0, x01); PKFMA(aB, wB1, x23);
        #pragma unroll
        for (int j = 0; j < 16; ++j) {      // 2 independent pk chains
            PKFMA(aA, whhA[j], h2[j]);
            PKFMA(aB, whhB[j], h2[j]);
        }
        const float a0 = aA.x + aA.y;       // i or f pre-activation
        const float a1 = aB.x + aB.y;       // g or o pre-activation
        const float act0 = RCP(1.0f + EXP2(-LOG2E * a0));          // sigmoid
        const float act1 = fmaf(B1, RCP(1.0f + EXP2(S1 * a1)), A1);
        const float xo0 = __shfl_xor(act0, 32, 64);
        const float xo1 = __shfl_xor(act1, 32, 64);
        const float i_ = isH ? xo0  : act0;
        const float f_ = isH ? act0 : xo0;
        const float g_ = isH ? xo1  : act1;
        const float o_ = isH ? act1 : xo1;
        c = fmaf(f_, c, i_ * g_);
        const float th = fmaf(-2.0f, RCP(1.0f + EXP2((2.0f * LOG2E) * c)), 1.0f);
        hk = o_ * th;                       // identical in lanes k and k+32
        if (!isH) hx[wv][k] = hk;           // exec-masked write, wave-private row
        const v2f* hr = reinterpret_cast<const v2f*>(&hx[wv][0]);
        #pragma unroll
        for (int j = 0; j < 16; ++j) h2[j] = hr[j];   // broadcast reads
    };

    // ---------------- encoder (x prefetched one step ahead) ----------------
    float4 x = poses4[el];                  // wave-uniform address
    for (int t = 0; t < T_enc; ++t) {
        float4 xn = x;
        if (t + 1 < T_enc) xn = poses4[(size_t)(t + 1) * B + el];
        lstm_step((v2f){x.x, x.y}, (v2f){x.z, x.w});
        x = xn;
    }
    const v2f p01 = {x.x, x.y};             // poses[-1][:,:2], constant in decode

    float v1 = wd1 * hk, v2 = wd2 * hk;     // vel rows 1,2 (row 0 unused)
    REDUCE32(v1); REDUCE32(v2);

    // ---------------- decoder ----------------
    for (int t = 0; t < T_dec; ++t) {
        const float rn = rsqrtf(v1 * v1 + v2 * v2);
        const float cs = v1 * rn, sn = v2 * rn;
        if (lane == 0) out4[(size_t)t * B + el] = make_float4(p01.x, p01.y, cs, sn);
        lstm_step(p01, (v2f){cs, sn});
        v1 = wd1 * hk; v2 = wd2 * hk;
        REDUCE32(v1); REDUCE32(v2);
    }
}

extern "C" void kernel_launch(void* const* d_in, const int* in_sizes, int n_in,
                              void* d_out, int out_size, void* d_ws, size_t ws_size,
                              hipStream_t stream) {
    const float* poses   = (const float*)d_in[0];
    // d_in[1] = deltas: values unused by the reference decoder (only length matters)
    const float* W_ih    = (const float*)d_in[2];
    const float* W_hh    = (const float*)d_in[3];
    const float* W_dense = (const float*)d_in[4];
    float* out = (float*)d_out;

    const int T_enc = 64;                       // fixed by the reference setup
    const int B     = in_sizes[0] / (T_enc * 4);
    const int T_dec = out_size / (B * 4);       // n_new_poses

    dim3 grid(B / 4), block(256);
    hipLaunchKernelGGL(lstm_gatesplit, grid, block, 0, stream,
                       poses, W_ih, W_hh, W_dense, out, B, T_enc, T_dec);
}